// Round 2
// baseline (939.410 us; speedup 1.0000x reference)
//
#include <hip/hip_runtime.h>

// =====================================================================
// GCN forward: 3x GCNConv(+self-loops, sym-norm) with residual+LN+ReLU
// Strategy: build dst-CSR once per call, pull-style aggregation
// (wave-per-node), fused bias+residual+LayerNorm+ReLU epilogue.
// All fp32. edge_index arrives as int32 (harness converts int64->int32).
// =====================================================================

// ---------------- CSR build ----------------
__global__ void k_count(const int* __restrict__ ei, int E, int n, int* __restrict__ cnt){
  int e = blockIdx.x*blockDim.x + threadIdx.x;
  if (e < E){
    int d = ei[E + e];
    if ((unsigned)d < (unsigned)n) atomicAdd(&cnt[d], 1);
  }
}

__global__ void k_dinv(const int* __restrict__ cnt, float* __restrict__ dinv, int n){
  int i = blockIdx.x*blockDim.x + threadIdx.x;
  if (i < n) dinv[i] = rsqrtf((float)cnt[i] + 1.0f);   // +1 self-loop
}

__device__ __forceinline__ int wave_incl_scan(int v, int lane){
#pragma unroll
  for (int off = 1; off < 64; off <<= 1){
    int t = __shfl_up(v, off, 64);
    if (lane >= off) v += t;
  }
  return v;
}

__global__ void k_scan_a(const int* __restrict__ cnt, int* __restrict__ ex,
                         int* __restrict__ bsum, int n){
  int tid = threadIdx.x;
  int gid = blockIdx.x*1024 + tid;
  int lane = tid & 63, wid = tid >> 6;
  int v = (gid < n) ? cnt[gid] : 0;
  int incl = wave_incl_scan(v, lane);
  __shared__ int ws[16];
  if (lane == 63) ws[wid] = incl;
  __syncthreads();
  if (wid == 0){
    int w = (lane < 16) ? ws[lane] : 0;
    w = wave_incl_scan(w, lane);
    if (lane < 16) ws[lane] = w;
  }
  __syncthreads();
  int wofs = wid ? ws[wid-1] : 0;
  if (gid < n) ex[gid] = wofs + incl - v;
  if (tid == 1023) bsum[blockIdx.x] = wofs + incl;
}

__global__ void k_scan_b(int* __restrict__ bsum, int nb){
  int tid = threadIdx.x;
  int lane = tid & 63, wid = tid >> 6;
  int v = (tid < nb) ? bsum[tid] : 0;
  int incl = wave_incl_scan(v, lane);
  __shared__ int ws[16];
  if (lane == 63) ws[wid] = incl;
  __syncthreads();
  if (wid == 0){
    int w = (lane < 16) ? ws[lane] : 0;
    w = wave_incl_scan(w, lane);
    if (lane < 16) ws[lane] = w;
  }
  __syncthreads();
  int wofs = wid ? ws[wid-1] : 0;
  if (tid < nb) bsum[tid] = wofs + incl - v;
}

__global__ void k_scan_c(int* __restrict__ rp, const int* __restrict__ bsum, int n, int E){
  int gid = blockIdx.x*1024 + threadIdx.x;
  if (gid < n) rp[gid] += bsum[blockIdx.x];
  if (blockIdx.x == 0 && threadIdx.x == 0) rp[n] = E;
}

__global__ void k_scatter(const int* __restrict__ ei, int E, int n,
                          const int* __restrict__ rp, int* __restrict__ fill,
                          int* __restrict__ col){
  int e = blockIdx.x*blockDim.x + threadIdx.x;
  if (e < E){
    int d = ei[E + e];
    int s = ei[e];
    if ((unsigned)d < (unsigned)n && (unsigned)s < (unsigned)n){
      int pos = rp[d] + atomicAdd(&fill[d], 1);
      col[pos] = s;
    }
  }
}

// ---------------- input GEMM: [n,64]@[64,128] + bias, ReLU ----------------
__global__ __launch_bounds__(256) void k_gemm_in(const float* __restrict__ X,
    const float* __restrict__ W, const float* __restrict__ b,
    float* __restrict__ out, int n){
  __shared__ float Wl[64*128];
  int tid = threadIdx.x;
  for (int i = tid; i < 64*128/4; i += 256)
    ((float4*)Wl)[i] = ((const float4*)W)[i];
  __syncthreads();
  int rg = tid >> 4, tx = tid & 15;
  int r0 = blockIdx.x*64 + rg*4;
  int c0 = tx*8;
  float acc[4][8];
#pragma unroll
  for (int i=0;i<4;i++)
#pragma unroll
    for (int j=0;j<8;j++) acc[i][j]=0.f;
  int rr[4];
#pragma unroll
  for (int i=0;i<4;i++) rr[i] = min(r0+i, n-1);
#pragma unroll 4
  for (int k=0;k<64;k++){
    float4 b0 = *(const float4*)&Wl[k*128 + c0];
    float4 b1 = *(const float4*)&Wl[k*128 + c0 + 4];
#pragma unroll
    for (int i=0;i<4;i++){
      float a = X[rr[i]*64 + k];
      acc[i][0] = fmaf(a,b0.x,acc[i][0]); acc[i][1] = fmaf(a,b0.y,acc[i][1]);
      acc[i][2] = fmaf(a,b0.z,acc[i][2]); acc[i][3] = fmaf(a,b0.w,acc[i][3]);
      acc[i][4] = fmaf(a,b1.x,acc[i][4]); acc[i][5] = fmaf(a,b1.y,acc[i][5]);
      acc[i][6] = fmaf(a,b1.z,acc[i][6]); acc[i][7] = fmaf(a,b1.w,acc[i][7]);
    }
  }
  float4 bb0 = *(const float4*)&b[c0];
  float4 bb1 = *(const float4*)&b[c0+4];
#pragma unroll
  for (int i=0;i<4;i++){
    int r = r0 + i;
    if (r < n){
      float4 o0, o1;
      o0.x = fmaxf(acc[i][0]+bb0.x, 0.f); o0.y = fmaxf(acc[i][1]+bb0.y, 0.f);
      o0.z = fmaxf(acc[i][2]+bb0.z, 0.f); o0.w = fmaxf(acc[i][3]+bb0.w, 0.f);
      o1.x = fmaxf(acc[i][4]+bb1.x, 0.f); o1.y = fmaxf(acc[i][5]+bb1.y, 0.f);
      o1.z = fmaxf(acc[i][6]+bb1.z, 0.f); o1.w = fmaxf(acc[i][7]+bb1.w, 0.f);
      *(float4*)&out[r*128 + c0]     = o0;
      *(float4*)&out[r*128 + c0 + 4] = o1;
    }
  }
}

// ---------------- conv GEMM: [n,128]@[128,128] (no bias) ----------------
__global__ __launch_bounds__(256) void k_gemm_h(const float* __restrict__ A,
    const float* __restrict__ W, float* __restrict__ out, int n){
  __shared__ float Wl[128*128];
  int tid = threadIdx.x;
  for (int i = tid; i < 128*128/4; i += 256)
    ((float4*)Wl)[i] = ((const float4*)W)[i];
  __syncthreads();
  int rg = tid >> 4, tx = tid & 15;
  int r0 = blockIdx.x*64 + rg*4;
  int c0 = tx*8;
  float acc[4][8];
#pragma unroll
  for (int i=0;i<4;i++)
#pragma unroll
    for (int j=0;j<8;j++) acc[i][j]=0.f;
  int rr[4];
#pragma unroll
  for (int i=0;i<4;i++) rr[i] = min(r0+i, n-1);
#pragma unroll 4
  for (int k=0;k<128;k++){
    float4 b0 = *(const float4*)&Wl[k*128 + c0];
    float4 b1 = *(const float4*)&Wl[k*128 + c0 + 4];
#pragma unroll
    for (int i=0;i<4;i++){
      float a = A[rr[i]*128 + k];
      acc[i][0] = fmaf(a,b0.x,acc[i][0]); acc[i][1] = fmaf(a,b0.y,acc[i][1]);
      acc[i][2] = fmaf(a,b0.z,acc[i][2]); acc[i][3] = fmaf(a,b0.w,acc[i][3]);
      acc[i][4] = fmaf(a,b1.x,acc[i][4]); acc[i][5] = fmaf(a,b1.y,acc[i][5]);
      acc[i][6] = fmaf(a,b1.z,acc[i][6]); acc[i][7] = fmaf(a,b1.w,acc[i][7]);
    }
  }
#pragma unroll
  for (int i=0;i<4;i++){
    int r = r0 + i;
    if (r < n){
      float4 o0 = {acc[i][0],acc[i][1],acc[i][2],acc[i][3]};
      float4 o1 = {acc[i][4],acc[i][5],acc[i][6],acc[i][7]};
      *(float4*)&out[r*128 + c0]     = o0;
      *(float4*)&out[r*128 + c0 + 4] = o1;
    }
  }
}

// ---- aggregation (pull, wave/node) + bias + residual + LN + ReLU, in-place h ----
__global__ __launch_bounds__(256) void k_agg_ln(const float* __restrict__ hp,
    float* __restrict__ h, const float* __restrict__ dinv,
    const int* __restrict__ rp, const int* __restrict__ col,
    const float* __restrict__ bc, const float* __restrict__ g,
    const float* __restrict__ be, int n){
  int node = blockIdx.x*4 + (threadIdx.x >> 6);
  int lane = threadIdx.x & 63;
  if (node >= n) return;
  float di = dinv[node];
  const float2* hp2 = (const float2*)hp;
  float2 a = hp2[node*64 + lane];
  float accx = a.x * di * di;      // self-loop term
  float accy = a.y * di * di;
  int e = rp[node], end = rp[node+1];
  for (; e < end; ++e){
    int s = col[e];
    float w = dinv[s] * di;
    float2 v = hp2[s*64 + lane];
    accx = fmaf(v.x, w, accx);
    accy = fmaf(v.y, w, accy);
  }
  float2 bb  = ((const float2*)bc)[lane];
  float2 idv = ((const float2*)h)[node*64 + lane];
  float vx = accx + bb.x + idv.x;
  float vy = accy + bb.y + idv.y;
  float s1 = vx + vy;
#pragma unroll
  for (int off=32; off; off>>=1) s1 += __shfl_xor(s1, off, 64);
  float mu = s1 * (1.0f/128.0f);
  float dx = vx - mu, dy = vy - mu;
  float q = dx*dx + dy*dy;
#pragma unroll
  for (int off=32; off; off>>=1) q += __shfl_xor(q, off, 64);
  float rstd = rsqrtf(q * (1.0f/128.0f) + 1e-5f);
  float2 gg = ((const float2*)g)[lane];
  float2 eb = ((const float2*)be)[lane];
  float ox = fmaxf(fmaf(dx*rstd, gg.x, eb.x), 0.f);
  float oy = fmaxf(fmaf(dy*rstd, gg.y, eb.y), 0.f);
  ((float2*)h)[node*64 + lane] = make_float2(ox, oy);
}

// ---------------- output GEMM: [n,128]@[128,2] + bias ----------------
__global__ __launch_bounds__(256) void k_gemm_out(const float* __restrict__ hA,
    const float* __restrict__ Wo, const float* __restrict__ bo,
    float* __restrict__ out, int n){
  int node = blockIdx.x*4 + (threadIdx.x >> 6);
  int lane = threadIdx.x & 63;
  if (node >= n) return;
  float2 v = ((const float2*)hA)[node*64 + lane];
  float4 w = ((const float4*)Wo)[lane];   // rows 2l,2l+1 of [128,2]
  float p0 = v.x*w.x + v.y*w.z;
  float p1 = v.x*w.y + v.y*w.w;
#pragma unroll
  for (int off=32; off; off>>=1){
    p0 += __shfl_xor(p0, off, 64);
    p1 += __shfl_xor(p1, off, 64);
  }
  if (lane == 0){
    out[node*2+0] = p0 + bo[0];
    out[node*2+1] = p1 + bo[1];
  }
}

// =====================================================================
extern "C" void kernel_launch(void* const* d_in, const int* in_sizes, int n_in,
                              void* d_out, int out_size, void* d_ws, size_t ws_size,
                              hipStream_t stream){
  const float* x      = (const float*)d_in[0];
  const int*   ei     = (const int*)d_in[1];      // int32 on device
  const float* W_in   = (const float*)d_in[2];
  const float* b_in   = (const float*)d_in[3];
  const float* W_out  = (const float*)d_in[4];
  const float* b_out  = (const float*)d_in[5];
  const float* Wc[3] = {(const float*)d_in[6],  (const float*)d_in[10], (const float*)d_in[14]};
  const float* bc[3] = {(const float*)d_in[7],  (const float*)d_in[11], (const float*)d_in[15]};
  const float* g[3]  = {(const float*)d_in[8],  (const float*)d_in[12], (const float*)d_in[16]};
  const float* be[3] = {(const float*)d_in[9],  (const float*)d_in[13], (const float*)d_in[17]};
  const int n = in_sizes[0] / 64;
  const int E = in_sizes[1] / 2;

  char* ws = (char*)d_ws;
  size_t off = 0;
  auto alloc = [&](size_t bytes)->char*{
    char* p = ws + off;
    off += (bytes + 511) & ~size_t(511);
    return p;
  };
  float* dinv = (float*)alloc((size_t)n*4);
  int*   cnt  = (int*)  alloc((size_t)n*4);
  int*   rp   = (int*)  alloc((size_t)(n+1)*4);
  int*   fill = (int*)  alloc((size_t)n*4);
  int*   bsum = (int*)  alloc(4096);
  int*   col  = (int*)  alloc((size_t)E*4);
  float* hA   = (float*)alloc((size_t)n*128*4);
  float* hB   = (float*)alloc((size_t)n*128*4);
  (void)ws_size; (void)n_in; (void)out_size;

  hipMemsetAsync(cnt,  0, (size_t)n*4, stream);
  hipMemsetAsync(fill, 0, (size_t)n*4, stream);

  int nb = (n + 1023)/1024;
  k_count  <<<(E+255)/256, 256, 0, stream>>>(ei, E, n, cnt);
  k_dinv   <<<(n+255)/256, 256, 0, stream>>>(cnt, dinv, n);
  k_scan_a <<<nb, 1024, 0, stream>>>(cnt, rp, bsum, n);
  k_scan_b <<<1, 1024, 0, stream>>>(bsum, nb);
  k_scan_c <<<nb, 1024, 0, stream>>>(rp, bsum, n, E);
  k_scatter<<<(E+255)/256, 256, 0, stream>>>(ei, E, n, rp, fill, col);

  k_gemm_in<<<(n+63)/64, 256, 0, stream>>>(x, W_in, b_in, hA, n);
  for (int l = 0; l < 3; ++l){
    k_gemm_h <<<(n+63)/64, 256, 0, stream>>>(hA, Wc[l], hB, n);
    k_agg_ln <<<(n+3)/4, 256, 0, stream>>>(hB, hA, dinv, rp, col, bc[l], g[l], be[l], n);
  }
  k_gemm_out<<<(n+3)/4, 256, 0, stream>>>(hA, W_out, b_out, (float*)d_out, n);
}

// Round 3
// 655.542 us; speedup vs baseline: 1.4330x; 1.4330x over previous
//
#include <hip/hip_runtime.h>

// =====================================================================
// GCN forward: 3x GCNConv(+self-loops, sym-norm) with residual+LN+ReLU
// dst-CSR build, pull aggregation (wave/node) over bf16 rows pre-scaled
// by dinv[src] (halves gather bytes, kills per-edge dinv load),
// fused bias+residual+LayerNorm+ReLU epilogue. Accumulation in fp32.
// =====================================================================

__device__ __forceinline__ unsigned short f2bf_rne(float f){
  unsigned x = __float_as_uint(f);
  unsigned r = (x + 0x7FFFu + ((x >> 16) & 1u)) >> 16;
  return (unsigned short)r;
}

// ---------------- CSR build ----------------
__global__ void k_count(const int* __restrict__ ei, int E, int n, int* __restrict__ cnt){
  int e = blockIdx.x*blockDim.x + threadIdx.x;
  if (e < E){
    int d = ei[E + e];
    if ((unsigned)d < (unsigned)n) atomicAdd(&cnt[d], 1);
  }
}

__global__ void k_dinv(const int* __restrict__ cnt, float* __restrict__ dinv, int n){
  int i = blockIdx.x*blockDim.x + threadIdx.x;
  if (i < n) dinv[i] = rsqrtf((float)cnt[i] + 1.0f);   // +1 self-loop
}

__device__ __forceinline__ int wave_incl_scan(int v, int lane){
#pragma unroll
  for (int off = 1; off < 64; off <<= 1){
    int t = __shfl_up(v, off, 64);
    if (lane >= off) v += t;
  }
  return v;
}

__global__ void k_scan_a(const int* __restrict__ cnt, int* __restrict__ ex,
                         int* __restrict__ bsum, int n){
  int tid = threadIdx.x;
  int gid = blockIdx.x*1024 + tid;
  int lane = tid & 63, wid = tid >> 6;
  int v = (gid < n) ? cnt[gid] : 0;
  int incl = wave_incl_scan(v, lane);
  __shared__ int ws[16];
  if (lane == 63) ws[wid] = incl;
  __syncthreads();
  if (wid == 0){
    int w = (lane < 16) ? ws[lane] : 0;
    w = wave_incl_scan(w, lane);
    if (lane < 16) ws[lane] = w;
  }
  __syncthreads();
  int wofs = wid ? ws[wid-1] : 0;
  if (gid < n) ex[gid] = wofs + incl - v;
  if (tid == 1023) bsum[blockIdx.x] = wofs + incl;
}

__global__ void k_scan_b(int* __restrict__ bsum, int nb){
  int tid = threadIdx.x;
  int lane = tid & 63, wid = tid >> 6;
  int v = (tid < nb) ? bsum[tid] : 0;
  int incl = wave_incl_scan(v, lane);
  __shared__ int ws[16];
  if (lane == 63) ws[wid] = incl;
  __syncthreads();
  if (wid == 0){
    int w = (lane < 16) ? ws[lane] : 0;
    w = wave_incl_scan(w, lane);
    if (lane < 16) ws[lane] = w;
  }
  __syncthreads();
  int wofs = wid ? ws[wid-1] : 0;
  if (tid < nb) bsum[tid] = wofs + incl - v;
}

__global__ void k_scan_c(int* __restrict__ rp, const int* __restrict__ bsum, int n, int E){
  int gid = blockIdx.x*1024 + threadIdx.x;
  if (gid < n) rp[gid] += bsum[blockIdx.x];
  if (blockIdx.x == 0 && threadIdx.x == 0) rp[n] = E;
}

__global__ void k_scatter(const int* __restrict__ ei, int E, int n,
                          const int* __restrict__ rp, int* __restrict__ fill,
                          int* __restrict__ col){
  int e = blockIdx.x*blockDim.x + threadIdx.x;
  if (e < E){
    int d = ei[E + e];
    int s = ei[e];
    if ((unsigned)d < (unsigned)n && (unsigned)s < (unsigned)n){
      int pos = rp[d] + atomicAdd(&fill[d], 1);
      col[pos] = s;
    }
  }
}

// ---------------- input GEMM: [n,64]@[64,128] + bias, ReLU -> fp32 ----------------
__global__ __launch_bounds__(256) void k_gemm_in(const float* __restrict__ X,
    const float* __restrict__ W, const float* __restrict__ b,
    float* __restrict__ out, int n){
  __shared__ float Wl[64*128];
  int tid = threadIdx.x;
  for (int i = tid; i < 64*128/4; i += 256)
    ((float4*)Wl)[i] = ((const float4*)W)[i];
  __syncthreads();
  int rg = tid >> 4, tx = tid & 15;
  int r0 = blockIdx.x*64 + rg*4;
  int c0 = tx*8;
  float acc[4][8];
#pragma unroll
  for (int i=0;i<4;i++)
#pragma unroll
    for (int j=0;j<8;j++) acc[i][j]=0.f;
  int rr[4];
#pragma unroll
  for (int i=0;i<4;i++) rr[i] = min(r0+i, n-1);
#pragma unroll 4
  for (int k=0;k<64;k++){
    float4 b0 = *(const float4*)&Wl[k*128 + c0];
    float4 b1 = *(const float4*)&Wl[k*128 + c0 + 4];
#pragma unroll
    for (int i=0;i<4;i++){
      float a = X[rr[i]*64 + k];
      acc[i][0] = fmaf(a,b0.x,acc[i][0]); acc[i][1] = fmaf(a,b0.y,acc[i][1]);
      acc[i][2] = fmaf(a,b0.z,acc[i][2]); acc[i][3] = fmaf(a,b0.w,acc[i][3]);
      acc[i][4] = fmaf(a,b1.x,acc[i][4]); acc[i][5] = fmaf(a,b1.y,acc[i][5]);
      acc[i][6] = fmaf(a,b1.z,acc[i][6]); acc[i][7] = fmaf(a,b1.w,acc[i][7]);
    }
  }
  float4 bb0 = *(const float4*)&b[c0];
  float4 bb1 = *(const float4*)&b[c0+4];
#pragma unroll
  for (int i=0;i<4;i++){
    int r = r0 + i;
    if (r < n){
      float4 o0, o1;
      o0.x = fmaxf(acc[i][0]+bb0.x, 0.f); o0.y = fmaxf(acc[i][1]+bb0.y, 0.f);
      o0.z = fmaxf(acc[i][2]+bb0.z, 0.f); o0.w = fmaxf(acc[i][3]+bb0.w, 0.f);
      o1.x = fmaxf(acc[i][4]+bb1.x, 0.f); o1.y = fmaxf(acc[i][5]+bb1.y, 0.f);
      o1.z = fmaxf(acc[i][6]+bb1.z, 0.f); o1.w = fmaxf(acc[i][7]+bb1.w, 0.f);
      *(float4*)&out[r*128 + c0]     = o0;
      *(float4*)&out[r*128 + c0 + 4] = o1;
    }
  }
}

// ------- conv GEMM: [n,128]@[128,128], scale by dinv[row], store bf16 -------
__global__ __launch_bounds__(256) void k_gemm_h(const float* __restrict__ A,
    const float* __restrict__ W, const float* __restrict__ dinv,
    unsigned short* __restrict__ out, int n){
  __shared__ float Wl[128*128];
  int tid = threadIdx.x;
  for (int i = tid; i < 128*128/4; i += 256)
    ((float4*)Wl)[i] = ((const float4*)W)[i];
  __syncthreads();
  int rg = tid >> 4, tx = tid & 15;
  int r0 = blockIdx.x*64 + rg*4;
  int c0 = tx*8;
  float acc[4][8];
#pragma unroll
  for (int i=0;i<4;i++)
#pragma unroll
    for (int j=0;j<8;j++) acc[i][j]=0.f;
  int rr[4];
#pragma unroll
  for (int i=0;i<4;i++) rr[i] = min(r0+i, n-1);
#pragma unroll 4
  for (int k=0;k<128;k++){
    float4 b0 = *(const float4*)&Wl[k*128 + c0];
    float4 b1 = *(const float4*)&Wl[k*128 + c0 + 4];
#pragma unroll
    for (int i=0;i<4;i++){
      float a = A[rr[i]*128 + k];
      acc[i][0] = fmaf(a,b0.x,acc[i][0]); acc[i][1] = fmaf(a,b0.y,acc[i][1]);
      acc[i][2] = fmaf(a,b0.z,acc[i][2]); acc[i][3] = fmaf(a,b0.w,acc[i][3]);
      acc[i][4] = fmaf(a,b1.x,acc[i][4]); acc[i][5] = fmaf(a,b1.y,acc[i][5]);
      acc[i][6] = fmaf(a,b1.z,acc[i][6]); acc[i][7] = fmaf(a,b1.w,acc[i][7]);
    }
  }
#pragma unroll
  for (int i=0;i<4;i++){
    int r = r0 + i;
    if (r < n){
      float sc = dinv[r];
      uint4 o;
      o.x = (unsigned)f2bf_rne(acc[i][0]*sc) | ((unsigned)f2bf_rne(acc[i][1]*sc) << 16);
      o.y = (unsigned)f2bf_rne(acc[i][2]*sc) | ((unsigned)f2bf_rne(acc[i][3]*sc) << 16);
      o.z = (unsigned)f2bf_rne(acc[i][4]*sc) | ((unsigned)f2bf_rne(acc[i][5]*sc) << 16);
      o.w = (unsigned)f2bf_rne(acc[i][6]*sc) | ((unsigned)f2bf_rne(acc[i][7]*sc) << 16);
      *(uint4*)&out[(size_t)r*128 + c0] = o;
    }
  }
}

// ---- aggregation (pull, wave/node, bf16 rows) + bias + residual + LN + ReLU ----
__global__ __launch_bounds__(256) void k_agg_ln(const unsigned short* __restrict__ rows,
    float* __restrict__ h, const float* __restrict__ dinv,
    const int* __restrict__ rp, const int* __restrict__ col,
    const float* __restrict__ bc, const float* __restrict__ g,
    const float* __restrict__ be, int n){
  int node = blockIdx.x*4 + (threadIdx.x >> 6);
  int lane = threadIdx.x & 63;
  if (node >= n) return;
  const unsigned* R = (const unsigned*)rows;   // 1 uint = 2 bf16 feats
  // self-loop term: row[node] (already scaled by dinv[node])
  unsigned vs = R[(size_t)node*64 + lane];
  float ax = __uint_as_float(vs << 16);
  float ay = __uint_as_float(vs & 0xFFFF0000u);
  int e = rp[node], end = rp[node+1];
  // unroll-8: 8 independent row-gathers in flight
  for (; e + 8 <= end; e += 8){
    int s0 = col[e+0], s1 = col[e+1], s2 = col[e+2], s3 = col[e+3];
    int s4 = col[e+4], s5 = col[e+5], s6 = col[e+6], s7 = col[e+7];
    unsigned a0 = R[(size_t)s0*64 + lane];
    unsigned a1 = R[(size_t)s1*64 + lane];
    unsigned a2 = R[(size_t)s2*64 + lane];
    unsigned a3 = R[(size_t)s3*64 + lane];
    unsigned a4 = R[(size_t)s4*64 + lane];
    unsigned a5 = R[(size_t)s5*64 + lane];
    unsigned a6 = R[(size_t)s6*64 + lane];
    unsigned a7 = R[(size_t)s7*64 + lane];
    ax += __uint_as_float(a0 << 16); ay += __uint_as_float(a0 & 0xFFFF0000u);
    ax += __uint_as_float(a1 << 16); ay += __uint_as_float(a1 & 0xFFFF0000u);
    ax += __uint_as_float(a2 << 16); ay += __uint_as_float(a2 & 0xFFFF0000u);
    ax += __uint_as_float(a3 << 16); ay += __uint_as_float(a3 & 0xFFFF0000u);
    ax += __uint_as_float(a4 << 16); ay += __uint_as_float(a4 & 0xFFFF0000u);
    ax += __uint_as_float(a5 << 16); ay += __uint_as_float(a5 & 0xFFFF0000u);
    ax += __uint_as_float(a6 << 16); ay += __uint_as_float(a6 & 0xFFFF0000u);
    ax += __uint_as_float(a7 << 16); ay += __uint_as_float(a7 & 0xFFFF0000u);
  }
  for (; e < end; ++e){
    unsigned a0 = R[(size_t)col[e]*64 + lane];
    ax += __uint_as_float(a0 << 16); ay += __uint_as_float(a0 & 0xFFFF0000u);
  }
  float di = dinv[node];
  float2 bb  = ((const float2*)bc)[lane];
  float2 idv = ((const float2*)h)[(size_t)node*64 + lane];
  float vx = fmaf(ax, di, bb.x) + idv.x;
  float vy = fmaf(ay, di, bb.y) + idv.y;
  float s1 = vx + vy;
#pragma unroll
  for (int off=32; off; off>>=1) s1 += __shfl_xor(s1, off, 64);
  float mu = s1 * (1.0f/128.0f);
  float dx = vx - mu, dy = vy - mu;
  float q = dx*dx + dy*dy;
#pragma unroll
  for (int off=32; off; off>>=1) q += __shfl_xor(q, off, 64);
  float rstd = rsqrtf(q * (1.0f/128.0f) + 1e-5f);
  float2 gg = ((const float2*)g)[lane];
  float2 eb = ((const float2*)be)[lane];
  float ox = fmaxf(fmaf(dx*rstd, gg.x, eb.x), 0.f);
  float oy = fmaxf(fmaf(dy*rstd, gg.y, eb.y), 0.f);
  ((float2*)h)[(size_t)node*64 + lane] = make_float2(ox, oy);
}

// ---------------- output GEMM: [n,128]@[128,2] + bias ----------------
__global__ __launch_bounds__(256) void k_gemm_out(const float* __restrict__ hA,
    const float* __restrict__ Wo, const float* __restrict__ bo,
    float* __restrict__ out, int n){
  int node = blockIdx.x*4 + (threadIdx.x >> 6);
  int lane = threadIdx.x & 63;
  if (node >= n) return;
  float2 v = ((const float2*)hA)[(size_t)node*64 + lane];
  float4 w = ((const float4*)Wo)[lane];   // rows 2l,2l+1 of [128,2]
  float p0 = v.x*w.x + v.y*w.z;
  float p1 = v.x*w.y + v.y*w.w;
#pragma unroll
  for (int off=32; off; off>>=1){
    p0 += __shfl_xor(p0, off, 64);
    p1 += __shfl_xor(p1, off, 64);
  }
  if (lane == 0){
    out[node*2+0] = p0 + bo[0];
    out[node*2+1] = p1 + bo[1];
  }
}

// =====================================================================
extern "C" void kernel_launch(void* const* d_in, const int* in_sizes, int n_in,
                              void* d_out, int out_size, void* d_ws, size_t ws_size,
                              hipStream_t stream){
  const float* x      = (const float*)d_in[0];
  const int*   ei     = (const int*)d_in[1];      // int32 on device
  const float* W_in   = (const float*)d_in[2];
  const float* b_in   = (const float*)d_in[3];
  const float* W_out  = (const float*)d_in[4];
  const float* b_out  = (const float*)d_in[5];
  const float* Wc[3] = {(const float*)d_in[6],  (const float*)d_in[10], (const float*)d_in[14]};
  const float* bc[3] = {(const float*)d_in[7],  (const float*)d_in[11], (const float*)d_in[15]};
  const float* g[3]  = {(const float*)d_in[8],  (const float*)d_in[12], (const float*)d_in[16]};
  const float* be[3] = {(const float*)d_in[9],  (const float*)d_in[13], (const float*)d_in[17]};
  const int n = in_sizes[0] / 64;
  const int E = in_sizes[1] / 2;

  char* ws = (char*)d_ws;
  size_t off = 0;
  auto alloc = [&](size_t bytes)->char*{
    char* p = ws + off;
    off += (bytes + 511) & ~size_t(511);
    return p;
  };
  float* dinv = (float*)alloc((size_t)n*4);
  int*   cnt  = (int*)  alloc((size_t)n*4);
  int*   rp   = (int*)  alloc((size_t)(n+1)*4);
  int*   fill = (int*)  alloc((size_t)n*4);
  int*   bsum = (int*)  alloc(4096);
  int*   col  = (int*)  alloc((size_t)E*4);
  float* hA   = (float*)alloc((size_t)n*128*4);
  unsigned short* hBs = (unsigned short*)alloc((size_t)n*128*2);
  (void)ws_size; (void)n_in; (void)out_size;

  hipMemsetAsync(cnt,  0, (size_t)n*4, stream);
  hipMemsetAsync(fill, 0, (size_t)n*4, stream);

  int nb = (n + 1023)/1024;
  k_count  <<<(E+255)/256, 256, 0, stream>>>(ei, E, n, cnt);
  k_dinv   <<<(n+255)/256, 256, 0, stream>>>(cnt, dinv, n);
  k_scan_a <<<nb, 1024, 0, stream>>>(cnt, rp, bsum, n);
  k_scan_b <<<1, 1024, 0, stream>>>(bsum, nb);
  k_scan_c <<<nb, 1024, 0, stream>>>(rp, bsum, n, E);
  k_scatter<<<(E+255)/256, 256, 0, stream>>>(ei, E, n, rp, fill, col);

  k_gemm_in<<<(n+63)/64, 256, 0, stream>>>(x, W_in, b_in, hA, n);
  for (int l = 0; l < 3; ++l){
    k_gemm_h <<<(n+63)/64, 256, 0, stream>>>(hA, Wc[l], dinv, hBs, n);
    k_agg_ln <<<(n+3)/4, 256, 0, stream>>>(hBs, hA, dinv, rp, col, bc[l], g[l], be[l], n);
  }
  k_gemm_out<<<(n+3)/4, 256, 0, stream>>>(hA, W_out, b_out, (float*)d_out, n);
}

// Round 4
// 505.891 us; speedup vs baseline: 1.8569x; 1.2958x over previous
//
#include <hip/hip_runtime.h>

// =====================================================================
// GCN forward: 3x GCNConv(+self-loops, sym-norm) + residual+LN+ReLU.
// h kept in bf16 end-to-end. conv GEMM = bf16 MFMA 16x16x32.
// Pull aggregation over dinv-prescaled bf16 rows, fused LN epilogue.
// =====================================================================

typedef __attribute__((ext_vector_type(8))) short short8;
typedef __attribute__((ext_vector_type(4))) float f32x4;

__device__ __forceinline__ unsigned short f2bf_rne(float f){
  unsigned x = __float_as_uint(f);
  unsigned r = (x + 0x7FFFu + ((x >> 16) & 1u)) >> 16;
  return (unsigned short)r;
}
__device__ __forceinline__ float bf_lo(unsigned u){ return __uint_as_float(u << 16); }
__device__ __forceinline__ float bf_hi(unsigned u){ return __uint_as_float(u & 0xFFFF0000u); }

// ---------------- CSR build ----------------
__global__ void k_count(const int* __restrict__ ei, int E, int n, int* __restrict__ cnt){
  int e = blockIdx.x*blockDim.x + threadIdx.x;
  if (e < E){
    int d = ei[E + e];
    if ((unsigned)d < (unsigned)n) atomicAdd(&cnt[d], 1);
  }
}

__global__ void k_dinv(const int* __restrict__ cnt, float* __restrict__ dinv, int n){
  int i = blockIdx.x*blockDim.x + threadIdx.x;
  if (i < n) dinv[i] = rsqrtf((float)cnt[i] + 1.0f);   // +1 self-loop
}

__device__ __forceinline__ int wave_incl_scan(int v, int lane){
#pragma unroll
  for (int off = 1; off < 64; off <<= 1){
    int t = __shfl_up(v, off, 64);
    if (lane >= off) v += t;
  }
  return v;
}

__global__ void k_scan_a(const int* __restrict__ cnt, int* __restrict__ ex,
                         int* __restrict__ bsum, int n){
  int tid = threadIdx.x;
  int gid = blockIdx.x*1024 + tid;
  int lane = tid & 63, wid = tid >> 6;
  int v = (gid < n) ? cnt[gid] : 0;
  int incl = wave_incl_scan(v, lane);
  __shared__ int ws[16];
  if (lane == 63) ws[wid] = incl;
  __syncthreads();
  if (wid == 0){
    int w = (lane < 16) ? ws[lane] : 0;
    w = wave_incl_scan(w, lane);
    if (lane < 16) ws[lane] = w;
  }
  __syncthreads();
  int wofs = wid ? ws[wid-1] : 0;
  if (gid < n) ex[gid] = wofs + incl - v;
  if (tid == 1023) bsum[blockIdx.x] = wofs + incl;
}

__global__ void k_scan_b(int* __restrict__ bsum, int nb){
  int tid = threadIdx.x;
  int lane = tid & 63, wid = tid >> 6;
  int v = (tid < nb) ? bsum[tid] : 0;
  int incl = wave_incl_scan(v, lane);
  __shared__ int ws[16];
  if (lane == 63) ws[wid] = incl;
  __syncthreads();
  if (wid == 0){
    int w = (lane < 16) ? ws[lane] : 0;
    w = wave_incl_scan(w, lane);
    if (lane < 16) ws[lane] = w;
  }
  __syncthreads();
  int wofs = wid ? ws[wid-1] : 0;
  if (tid < nb) bsum[tid] = wofs + incl - v;
}

__global__ void k_scan_c(int* __restrict__ rp, const int* __restrict__ bsum, int n, int E){
  int gid = blockIdx.x*1024 + threadIdx.x;
  if (gid < n) rp[gid] += bsum[blockIdx.x];
  if (blockIdx.x == 0 && threadIdx.x == 0) rp[n] = E;
}

__global__ void k_scatter(const int* __restrict__ ei, int E, int n,
                          const int* __restrict__ rp, int* __restrict__ fill,
                          int* __restrict__ col){
  int e = blockIdx.x*blockDim.x + threadIdx.x;
  if (e < E){
    int d = ei[E + e];
    int s = ei[e];
    if ((unsigned)d < (unsigned)n && (unsigned)s < (unsigned)n){
      int pos = rp[d] + atomicAdd(&fill[d], 1);
      col[pos] = s;
    }
  }
}

// ---------------- W transpose+convert: [128,128] f32 [k][c] -> bf16 [c][k] ----------
__global__ void k_prepW(const float* __restrict__ W, unsigned short* __restrict__ Wt){
  int idx = blockIdx.x*256 + threadIdx.x;   // 16384 elements
  int k = idx >> 7, c = idx & 127;
  Wt[c*128 + k] = f2bf_rne(W[idx]);
}

// ---------------- input GEMM: [n,64]@[64,128] + bias, ReLU -> bf16 h ----------------
__global__ __launch_bounds__(256) void k_gemm_in(const float* __restrict__ X,
    const float* __restrict__ W, const float* __restrict__ b,
    unsigned short* __restrict__ out, int n){
  __shared__ float Wl[64*128];
  int tid = threadIdx.x;
  for (int i = tid; i < 64*128/4; i += 256)
    ((float4*)Wl)[i] = ((const float4*)W)[i];
  __syncthreads();
  int rg = tid >> 4, tx = tid & 15;
  int r0 = blockIdx.x*64 + rg*4;
  int c0 = tx*8;
  float acc[4][8];
#pragma unroll
  for (int i=0;i<4;i++)
#pragma unroll
    for (int j=0;j<8;j++) acc[i][j]=0.f;
  int rr[4];
#pragma unroll
  for (int i=0;i<4;i++) rr[i] = min(r0+i, n-1);
#pragma unroll 4
  for (int k=0;k<64;k++){
    float4 b0 = *(const float4*)&Wl[k*128 + c0];
    float4 b1 = *(const float4*)&Wl[k*128 + c0 + 4];
#pragma unroll
    for (int i=0;i<4;i++){
      float a = X[rr[i]*64 + k];
      acc[i][0] = fmaf(a,b0.x,acc[i][0]); acc[i][1] = fmaf(a,b0.y,acc[i][1]);
      acc[i][2] = fmaf(a,b0.z,acc[i][2]); acc[i][3] = fmaf(a,b0.w,acc[i][3]);
      acc[i][4] = fmaf(a,b1.x,acc[i][4]); acc[i][5] = fmaf(a,b1.y,acc[i][5]);
      acc[i][6] = fmaf(a,b1.z,acc[i][6]); acc[i][7] = fmaf(a,b1.w,acc[i][7]);
    }
  }
  float4 bb0 = *(const float4*)&b[c0];
  float4 bb1 = *(const float4*)&b[c0+4];
#pragma unroll
  for (int i=0;i<4;i++){
    int r = r0 + i;
    if (r < n){
      float v0 = fmaxf(acc[i][0]+bb0.x, 0.f), v1 = fmaxf(acc[i][1]+bb0.y, 0.f);
      float v2 = fmaxf(acc[i][2]+bb0.z, 0.f), v3 = fmaxf(acc[i][3]+bb0.w, 0.f);
      float v4 = fmaxf(acc[i][4]+bb1.x, 0.f), v5 = fmaxf(acc[i][5]+bb1.y, 0.f);
      float v6 = fmaxf(acc[i][6]+bb1.z, 0.f), v7 = fmaxf(acc[i][7]+bb1.w, 0.f);
      uint4 o;
      o.x = (unsigned)f2bf_rne(v0) | ((unsigned)f2bf_rne(v1) << 16);
      o.y = (unsigned)f2bf_rne(v2) | ((unsigned)f2bf_rne(v3) << 16);
      o.z = (unsigned)f2bf_rne(v4) | ((unsigned)f2bf_rne(v5) << 16);
      o.w = (unsigned)f2bf_rne(v6) | ((unsigned)f2bf_rne(v7) << 16);
      *(uint4*)&out[(size_t)r*128 + c0] = o;
    }
  }
}

// ------- conv GEMM (MFMA bf16): rows = (h @ W) * dinv[row], bf16 out -------
// A frag: row = lane&15, k = (lane>>4)*8 + i  (+32*kk)
// B frag: col = lane&15, same k  -> read Wt[c][k] (c row-major), XOR-swizzled LDS
// C/D  : col = lane&15, row = (lane>>4)*4 + reg   [m89-verified]
__global__ __launch_bounds__(256) void k_gemm_h_mfma(
    const unsigned short* __restrict__ h,    // [n,128] bf16
    const unsigned short* __restrict__ Wt,   // [128,128] bf16 [c][k]
    const float* __restrict__ dinv,
    unsigned short* __restrict__ rows, int n){
  __shared__ unsigned short Wl[128*128];     // [c][16 chunks of 8], chunk swizzled by c&7
  int tid = threadIdx.x;
  for (int i = tid; i < 2048; i += 256){     // 2048 16B chunks
    int c = i >> 4, kc = i & 15;
    *(uint4*)&Wl[c*128 + (kc ^ (c & 7))*8] = *(const uint4*)&Wt[c*128 + kc*8];
  }
  __syncthreads();
  int wid = tid >> 6, lane = tid & 63;
  int r0 = blockIdx.x*64 + wid*16;
  int arow = r0 + (lane & 15);
  if (arow >= n) arow = n - 1;
  int kgrp = lane >> 4;
  f32x4 acc[8];
#pragma unroll
  for (int cf = 0; cf < 8; cf++) acc[cf] = (f32x4){0.f,0.f,0.f,0.f};
#pragma unroll
  for (int kk = 0; kk < 4; kk++){
    short8 afrag = *(const short8*)&h[(size_t)arow*128 + kk*32 + kgrp*8];
    int kc = kk*4 + kgrp;
#pragma unroll
    for (int cf = 0; cf < 8; cf++){
      int c = cf*16 + (lane & 15);
      short8 bfrag = *(const short8*)&Wl[c*128 + (kc ^ (c & 7))*8];
      acc[cf] = __builtin_amdgcn_mfma_f32_16x16x32_bf16(afrag, bfrag, acc[cf], 0, 0, 0);
    }
  }
  int rbase = r0 + (lane >> 4)*4;
  int colb = lane & 15;
#pragma unroll
  for (int reg = 0; reg < 4; reg++){
    int r = rbase + reg;
    if (r < n){
      float sc = dinv[r];
#pragma unroll
      for (int cf = 0; cf < 8; cf++)
        rows[(size_t)r*128 + cf*16 + colb] = f2bf_rne(acc[cf][reg]*sc);
    }
  }
}

// ---- aggregation (pull, wave/node, bf16 rows) + bias + residual + LN + ReLU ----
__global__ __launch_bounds__(256) void k_agg_ln(const unsigned short* __restrict__ rows,
    unsigned short* __restrict__ h, const float* __restrict__ dinv,
    const int* __restrict__ rp, const int* __restrict__ col,
    const float* __restrict__ bc, const float* __restrict__ g,
    const float* __restrict__ be, int n){
  int node = blockIdx.x*4 + (threadIdx.x >> 6);
  int lane = threadIdx.x & 63;
  if (node >= n) return;
  const unsigned* R = (const unsigned*)rows;   // 1 uint = 2 bf16 feats
  unsigned vs = R[(size_t)node*64 + lane];     // self-loop (pre-scaled)
  float ax = bf_lo(vs), ay = bf_hi(vs);
  int e = rp[node], end = rp[node+1];
  for (; e + 8 <= end; e += 8){
    int s0 = col[e+0], s1 = col[e+1], s2 = col[e+2], s3 = col[e+3];
    int s4 = col[e+4], s5 = col[e+5], s6 = col[e+6], s7 = col[e+7];
    unsigned a0 = R[(size_t)s0*64 + lane];
    unsigned a1 = R[(size_t)s1*64 + lane];
    unsigned a2 = R[(size_t)s2*64 + lane];
    unsigned a3 = R[(size_t)s3*64 + lane];
    unsigned a4 = R[(size_t)s4*64 + lane];
    unsigned a5 = R[(size_t)s5*64 + lane];
    unsigned a6 = R[(size_t)s6*64 + lane];
    unsigned a7 = R[(size_t)s7*64 + lane];
    ax += bf_lo(a0); ay += bf_hi(a0);
    ax += bf_lo(a1); ay += bf_hi(a1);
    ax += bf_lo(a2); ay += bf_hi(a2);
    ax += bf_lo(a3); ay += bf_hi(a3);
    ax += bf_lo(a4); ay += bf_hi(a4);
    ax += bf_lo(a5); ay += bf_hi(a5);
    ax += bf_lo(a6); ay += bf_hi(a6);
    ax += bf_lo(a7); ay += bf_hi(a7);
  }
  for (; e < end; ++e){
    unsigned a0 = R[(size_t)col[e]*64 + lane];
    ax += bf_lo(a0); ay += bf_hi(a0);
  }
  float di = dinv[node];
  float2 bb = ((const float2*)bc)[lane];
  unsigned* H = (unsigned*)h;
  unsigned iu = H[(size_t)node*64 + lane];
  float vx = fmaf(ax, di, bb.x) + bf_lo(iu);
  float vy = fmaf(ay, di, bb.y) + bf_hi(iu);
  float s1 = vx + vy;
#pragma unroll
  for (int off=32; off; off>>=1) s1 += __shfl_xor(s1, off, 64);
  float mu = s1 * (1.0f/128.0f);
  float dx = vx - mu, dy = vy - mu;
  float q = dx*dx + dy*dy;
#pragma unroll
  for (int off=32; off; off>>=1) q += __shfl_xor(q, off, 64);
  float rstd = rsqrtf(q * (1.0f/128.0f) + 1e-5f);
  float2 gg = ((const float2*)g)[lane];
  float2 eb = ((const float2*)be)[lane];
  float ox = fmaxf(fmaf(dx*rstd, gg.x, eb.x), 0.f);
  float oy = fmaxf(fmaf(dy*rstd, gg.y, eb.y), 0.f);
  H[(size_t)node*64 + lane] = (unsigned)f2bf_rne(ox) | ((unsigned)f2bf_rne(oy) << 16);
}

// ---------------- output GEMM: [n,128]@[128,2] + bias ----------------
__global__ __launch_bounds__(256) void k_gemm_out(const unsigned short* __restrict__ h,
    const float* __restrict__ Wo, const float* __restrict__ bo,
    float* __restrict__ out, int n){
  int node = blockIdx.x*4 + (threadIdx.x >> 6);
  int lane = threadIdx.x & 63;
  if (node >= n) return;
  unsigned u = ((const unsigned*)h)[(size_t)node*64 + lane];
  float x = bf_lo(u), y = bf_hi(u);
  float4 w = ((const float4*)Wo)[lane];   // rows 2l,2l+1 of [128,2]
  float p0 = x*w.x + y*w.z;
  float p1 = x*w.y + y*w.w;
#pragma unroll
  for (int off=32; off; off>>=1){
    p0 += __shfl_xor(p0, off, 64);
    p1 += __shfl_xor(p1, off, 64);
  }
  if (lane == 0){
    out[node*2+0] = p0 + bo[0];
    out[node*2+1] = p1 + bo[1];
  }
}

// =====================================================================
extern "C" void kernel_launch(void* const* d_in, const int* in_sizes, int n_in,
                              void* d_out, int out_size, void* d_ws, size_t ws_size,
                              hipStream_t stream){
  const float* x      = (const float*)d_in[0];
  const int*   ei     = (const int*)d_in[1];
  const float* W_in   = (const float*)d_in[2];
  const float* b_in   = (const float*)d_in[3];
  const float* W_out  = (const float*)d_in[4];
  const float* b_out  = (const float*)d_in[5];
  const float* Wc[3] = {(const float*)d_in[6],  (const float*)d_in[10], (const float*)d_in[14]};
  const float* bc[3] = {(const float*)d_in[7],  (const float*)d_in[11], (const float*)d_in[15]};
  const float* g[3]  = {(const float*)d_in[8],  (const float*)d_in[12], (const float*)d_in[16]};
  const float* be[3] = {(const float*)d_in[9],  (const float*)d_in[13], (const float*)d_in[17]};
  const int n = in_sizes[0] / 64;
  const int E = in_sizes[1] / 2;

  char* ws = (char*)d_ws;
  size_t off = 0;
  auto alloc = [&](size_t bytes)->char*{
    char* p = ws + off;
    off += (bytes + 511) & ~size_t(511);
    return p;
  };
  float* dinv = (float*)alloc((size_t)n*4);
  int*   cnt  = (int*)  alloc((size_t)n*4);
  int*   rp   = (int*)  alloc((size_t)(n+1)*4);
  int*   fill = (int*)  alloc((size_t)n*4);
  int*   bsum = (int*)  alloc(4096);
  int*   col  = (int*)  alloc((size_t)E*4);
  unsigned short* hB  = (unsigned short*)alloc((size_t)n*128*2);  // bf16 h
  unsigned short* rows= (unsigned short*)alloc((size_t)n*128*2);  // bf16 conv rows
  unsigned short* Wt[3];
  for (int l = 0; l < 3; ++l) Wt[l] = (unsigned short*)alloc(128*128*2);
  (void)ws_size; (void)n_in; (void)out_size;

  hipMemsetAsync(cnt,  0, (size_t)n*4, stream);
  hipMemsetAsync(fill, 0, (size_t)n*4, stream);

  int nb = (n + 1023)/1024;
  k_count  <<<(E+255)/256, 256, 0, stream>>>(ei, E, n, cnt);
  k_dinv   <<<(n+255)/256, 256, 0, stream>>>(cnt, dinv, n);
  k_scan_a <<<nb, 1024, 0, stream>>>(cnt, rp, bsum, n);
  k_scan_b <<<1, 1024, 0, stream>>>(bsum, nb);
  k_scan_c <<<nb, 1024, 0, stream>>>(rp, bsum, n, E);
  k_scatter<<<(E+255)/256, 256, 0, stream>>>(ei, E, n, rp, fill, col);
  for (int l = 0; l < 3; ++l)
    k_prepW<<<64, 256, 0, stream>>>(Wc[l], Wt[l]);

  k_gemm_in<<<(n+63)/64, 256, 0, stream>>>(x, W_in, b_in, hB, n);
  for (int l = 0; l < 3; ++l){
    k_gemm_h_mfma<<<(n+63)/64, 256, 0, stream>>>(hB, Wt[l], dinv, rows, n);
    k_agg_ln <<<(n+3)/4, 256, 0, stream>>>(rows, hB, dinv, rp, col, bc[l], g[l], be[l], n);
  }
  k_gemm_out<<<(n+3)/4, 256, 0, stream>>>(hB, W_out, b_out, (float*)d_out, n);
}

// Round 5
// 385.809 us; speedup vs baseline: 2.4349x; 1.3112x over previous
//
#include <hip/hip_runtime.h>

// =====================================================================
// GCN forward: 3x GCNConv(+self-loops, sym-norm) + residual+LN+ReLU.
// h kept in bf16 end-to-end. conv GEMM = bf16 MFMA 16x16x32.
// CSR build = bucketed counting sort (no global atomics, coalesced writes).
// Pull aggregation over dinv-prescaled bf16 rows, fused LN epilogue.
// =====================================================================

typedef __attribute__((ext_vector_type(8))) short short8;
typedef __attribute__((ext_vector_type(4))) float f32x4;

#define CHUNK 4096      // edges per bucketing block
#define BSH   9         // 512 nodes per bucket

__device__ __forceinline__ unsigned short f2bf_rne(float f){
  unsigned x = __float_as_uint(f);
  unsigned r = (x + 0x7FFFu + ((x >> 16) & 1u)) >> 16;
  return (unsigned short)r;
}
__device__ __forceinline__ float bf_lo(unsigned u){ return __uint_as_float(u << 16); }
__device__ __forceinline__ float bf_hi(unsigned u){ return __uint_as_float(u & 0xFFFF0000u); }

__device__ __forceinline__ int wave_incl_scan(int v, int lane){
#pragma unroll
  for (int off = 1; off < 64; off <<= 1){
    int t = __shfl_up(v, off, 64);
    if (lane >= off) v += t;
  }
  return v;
}

// exclusive scan over 256 threads; returns excl, *tot = block total
__device__ __forceinline__ int blockscan256(int v, int tid, int* tot){
  int lane = tid & 63, wid = tid >> 6;
  __shared__ int ws[4];
  int incl = wave_incl_scan(v, lane);
  if (lane == 63) ws[wid] = incl;
  __syncthreads();
  int w0 = ws[0], w1 = ws[1], w2 = ws[2], w3 = ws[3];
  __syncthreads();
  int wofs = (wid > 0 ? w0 : 0) + (wid > 1 ? w1 : 0) + (wid > 2 ? w2 : 0);
  *tot = w0 + w1 + w2 + w3;
  return wofs + incl - v;
}

// ---------------- CSR build: bucketed counting sort ----------------
// Pass A: per-chunk histogram over buckets
__global__ __launch_bounds__(256) void k_bhist(const int* __restrict__ ei, int E, int n,
                                               int NB, int NCH, int* __restrict__ bh){
  __shared__ int hist[512];
  int tid = threadIdx.x, b = blockIdx.x;
  for (int j = tid; j < NB; j += 256) hist[j] = 0;
  __syncthreads();
  int e0 = b*CHUNK;
  for (int i = tid; i < CHUNK; i += 256){
    int e = e0 + i;
    if (e < E){
      int d = ei[E + e];
      if ((unsigned)d < (unsigned)n) atomicAdd(&hist[d >> BSH], 1);
    }
  }
  __syncthreads();
  for (int j = tid; j < NB; j += 256) bh[(size_t)j*NCH + b] = hist[j];
}

// Pass B1: per-bucket exclusive scan across chunks (in place), totals out
__global__ __launch_bounds__(256) void k_scanB1(int* __restrict__ bh, int* __restrict__ btot,
                                                int NCH){
  int j = blockIdx.x, tid = threadIdx.x;
  int carry = 0;
  for (int base = 0; base < NCH; base += 256){
    int idx = base + tid;
    int v = (idx < NCH) ? bh[(size_t)j*NCH + idx] : 0;
    int tot, ex = blockscan256(v, tid, &tot);
    if (idx < NCH) bh[(size_t)j*NCH + idx] = carry + ex;
    carry += tot;
  }
  if (tid == 0) btot[j] = carry;
}

// Pass B2: exclusive scan over buckets -> bstart; also rp[n]=E, bstart[NB]=E
__global__ __launch_bounds__(512) void k_scanB2(const int* __restrict__ btot,
                                                int* __restrict__ bstart, int NB, int E,
                                                int* __restrict__ rp, int n){
  int tid = threadIdx.x;
  int lane = tid & 63, wid = tid >> 6;
  __shared__ int ws[8];
  int carry = 0;
  for (int base = 0; base < NB; base += 512){
    int idx = base + tid;
    int v = (idx < NB) ? btot[idx] : 0;
    int incl = wave_incl_scan(v, lane);
    if (lane == 63) ws[wid] = incl;
    __syncthreads();
    int wofs = 0;
#pragma unroll
    for (int i = 0; i < 8; i++) if (i < wid) wofs += ws[i];
    int tot = ws[0]+ws[1]+ws[2]+ws[3]+ws[4]+ws[5]+ws[6]+ws[7];
    __syncthreads();
    if (idx < NB) bstart[idx] = carry + wofs + incl - v;
    carry += tot;
  }
  if (tid == 0){ bstart[NB] = E; rp[n] = E; }
}

// Pass C: scatter (d,s) pairs into bucket-contiguous regions
__global__ __launch_bounds__(256) void k_bscatter(const int* __restrict__ ei, int E, int n,
    int NB, int NCH, const int* __restrict__ bh, const int* __restrict__ bstart,
    uint2* __restrict__ pairs){
  __shared__ int base_l[512];
  int tid = threadIdx.x, b = blockIdx.x;
  for (int j = tid; j < NB; j += 256) base_l[j] = bstart[j] + bh[(size_t)j*NCH + b];
  __syncthreads();
  int e0 = b*CHUNK;
  for (int i = tid; i < CHUNK; i += 256){
    int e = e0 + i;
    if (e < E){
      int d = ei[E + e], s = ei[e];
      if ((unsigned)d < (unsigned)n && (unsigned)s < (unsigned)n){
        int pos = atomicAdd(&base_l[d >> BSH], 1);
        pairs[pos] = make_uint2((unsigned)d, (unsigned)s);
      }
    }
  }
}

// Pass D: per-bucket node counts -> rp (global edge prefix) + dinv
__global__ __launch_bounds__(256) void k_brp(const uint2* __restrict__ pairs,
    const int* __restrict__ bstart, int* __restrict__ rp, float* __restrict__ dinv,
    int n, int NB){
  __shared__ int cnt_l[512];
  int j = blockIdx.x, tid = threadIdx.x;
  cnt_l[tid] = 0; cnt_l[tid + 256] = 0;
  __syncthreads();
  int p0 = bstart[j], p1 = bstart[j+1];
  for (int p = p0 + tid; p < p1; p += 256)
    atomicAdd(&cnt_l[pairs[p].x & 511], 1);
  __syncthreads();
  int carry = 0;
  int nbase = j << BSH;
  for (int base = 0; base < 512; base += 256){
    int v = cnt_l[base + tid];
    int tot, ex = blockscan256(v, tid, &tot);
    int node = nbase + base + tid;
    if (node < n){
      rp[node] = p0 + carry + ex;
      dinv[node] = rsqrtf((float)v + 1.0f);
    }
    carry += tot;
  }
}

// Pass E: per-bucket fill of col (dense writes within bucket's col window)
__global__ __launch_bounds__(256) void k_bfill(const uint2* __restrict__ pairs,
    const int* __restrict__ bstart, const int* __restrict__ rp,
    int* __restrict__ col, int n, int NB){
  __shared__ int loc[512];
  int j = blockIdx.x, tid = threadIdx.x;
  int nbase = j << BSH;
  for (int t = tid; t < 512; t += 256){
    int node = nbase + t;
    loc[t] = (node < n) ? rp[node] : 0;
  }
  __syncthreads();
  int p0 = bstart[j], p1 = bstart[j+1];
  for (int p = p0 + tid; p < p1; p += 256){
    uint2 pr = pairs[p];
    int pos = atomicAdd(&loc[pr.x & 511], 1);
    col[pos] = (int)pr.y;
  }
}

// ---------------- W transpose+convert: [128,128] f32 [k][c] -> bf16 [c][k] ----------
__global__ void k_prepW(const float* __restrict__ W, unsigned short* __restrict__ Wt){
  int idx = blockIdx.x*256 + threadIdx.x;   // 16384 elements
  int k = idx >> 7, c = idx & 127;
  Wt[c*128 + k] = f2bf_rne(W[idx]);
}

// ---------------- input GEMM: [n,64]@[64,128] + bias, ReLU -> bf16 h ----------------
__global__ __launch_bounds__(256) void k_gemm_in(const float* __restrict__ X,
    const float* __restrict__ W, const float* __restrict__ b,
    unsigned short* __restrict__ out, int n){
  __shared__ float Wl[64*128];
  int tid = threadIdx.x;
  for (int i = tid; i < 64*128/4; i += 256)
    ((float4*)Wl)[i] = ((const float4*)W)[i];
  __syncthreads();
  int rg = tid >> 4, tx = tid & 15;
  int r0 = blockIdx.x*64 + rg*4;
  int c0 = tx*8;
  float acc[4][8];
#pragma unroll
  for (int i=0;i<4;i++)
#pragma unroll
    for (int j=0;j<8;j++) acc[i][j]=0.f;
  int rr[4];
#pragma unroll
  for (int i=0;i<4;i++) rr[i] = min(r0+i, n-1);
#pragma unroll 4
  for (int k=0;k<64;k++){
    float4 b0 = *(const float4*)&Wl[k*128 + c0];
    float4 b1 = *(const float4*)&Wl[k*128 + c0 + 4];
#pragma unroll
    for (int i=0;i<4;i++){
      float a = X[rr[i]*64 + k];
      acc[i][0] = fmaf(a,b0.x,acc[i][0]); acc[i][1] = fmaf(a,b0.y,acc[i][1]);
      acc[i][2] = fmaf(a,b0.z,acc[i][2]); acc[i][3] = fmaf(a,b0.w,acc[i][3]);
      acc[i][4] = fmaf(a,b1.x,acc[i][4]); acc[i][5] = fmaf(a,b1.y,acc[i][5]);
      acc[i][6] = fmaf(a,b1.z,acc[i][6]); acc[i][7] = fmaf(a,b1.w,acc[i][7]);
    }
  }
  float4 bb0 = *(const float4*)&b[c0];
  float4 bb1 = *(const float4*)&b[c0+4];
#pragma unroll
  for (int i=0;i<4;i++){
    int r = r0 + i;
    if (r < n){
      float v0 = fmaxf(acc[i][0]+bb0.x, 0.f), v1 = fmaxf(acc[i][1]+bb0.y, 0.f);
      float v2 = fmaxf(acc[i][2]+bb0.z, 0.f), v3 = fmaxf(acc[i][3]+bb0.w, 0.f);
      float v4 = fmaxf(acc[i][4]+bb1.x, 0.f), v5 = fmaxf(acc[i][5]+bb1.y, 0.f);
      float v6 = fmaxf(acc[i][6]+bb1.z, 0.f), v7 = fmaxf(acc[i][7]+bb1.w, 0.f);
      uint4 o;
      o.x = (unsigned)f2bf_rne(v0) | ((unsigned)f2bf_rne(v1) << 16);
      o.y = (unsigned)f2bf_rne(v2) | ((unsigned)f2bf_rne(v3) << 16);
      o.z = (unsigned)f2bf_rne(v4) | ((unsigned)f2bf_rne(v5) << 16);
      o.w = (unsigned)f2bf_rne(v6) | ((unsigned)f2bf_rne(v7) << 16);
      *(uint4*)&out[(size_t)r*128 + c0] = o;
    }
  }
}

// ------- conv GEMM (MFMA bf16): rows = (h @ W) * dinv[row], bf16 out -------
__global__ __launch_bounds__(256) void k_gemm_h_mfma(
    const unsigned short* __restrict__ h,    // [n,128] bf16
    const unsigned short* __restrict__ Wt,   // [128,128] bf16 [c][k]
    const float* __restrict__ dinv,
    unsigned short* __restrict__ rows, int n){
  __shared__ unsigned short Wl[128*128];
  int tid = threadIdx.x;
  for (int i = tid; i < 2048; i += 256){
    int c = i >> 4, kc = i & 15;
    *(uint4*)&Wl[c*128 + (kc ^ (c & 7))*8] = *(const uint4*)&Wt[c*128 + kc*8];
  }
  __syncthreads();
  int wid = tid >> 6, lane = tid & 63;
  int r0 = blockIdx.x*64 + wid*16;
  int arow = r0 + (lane & 15);
  if (arow >= n) arow = n - 1;
  int kgrp = lane >> 4;
  f32x4 acc[8];
#pragma unroll
  for (int cf = 0; cf < 8; cf++) acc[cf] = (f32x4){0.f,0.f,0.f,0.f};
#pragma unroll
  for (int kk = 0; kk < 4; kk++){
    short8 afrag = *(const short8*)&h[(size_t)arow*128 + kk*32 + kgrp*8];
    int kc = kk*4 + kgrp;
#pragma unroll
    for (int cf = 0; cf < 8; cf++){
      int c = cf*16 + (lane & 15);
      short8 bfrag = *(const short8*)&Wl[c*128 + (kc ^ (c & 7))*8];
      acc[cf] = __builtin_amdgcn_mfma_f32_16x16x32_bf16(afrag, bfrag, acc[cf], 0, 0, 0);
    }
  }
  int rbase = r0 + (lane >> 4)*4;
  int colb = lane & 15;
#pragma unroll
  for (int reg = 0; reg < 4; reg++){
    int r = rbase + reg;
    if (r < n){
      float sc = dinv[r];
#pragma unroll
      for (int cf = 0; cf < 8; cf++)
        rows[(size_t)r*128 + cf*16 + colb] = f2bf_rne(acc[cf][reg]*sc);
    }
  }
}

// ---- aggregation (pull, wave/node, bf16 rows) + bias + residual + LN + ReLU ----
__global__ __launch_bounds__(256) void k_agg_ln(const unsigned short* __restrict__ rows,
    unsigned short* __restrict__ h, const float* __restrict__ dinv,
    const int* __restrict__ rp, const int* __restrict__ col,
    const float* __restrict__ bc, const float* __restrict__ g,
    const float* __restrict__ be, int n){
  int node = blockIdx.x*4 + (threadIdx.x >> 6);
  int lane = threadIdx.x & 63;
  if (node >= n) return;
  const unsigned* R = (const unsigned*)rows;
  unsigned vs = R[(size_t)node*64 + lane];
  float ax = bf_lo(vs), ay = bf_hi(vs);
  int e = rp[node], end = rp[node+1];
  for (; e + 8 <= end; e += 8){
    int s0 = col[e+0], s1 = col[e+1], s2 = col[e+2], s3 = col[e+3];
    int s4 = col[e+4], s5 = col[e+5], s6 = col[e+6], s7 = col[e+7];
    unsigned a0 = R[(size_t)s0*64 + lane];
    unsigned a1 = R[(size_t)s1*64 + lane];
    unsigned a2 = R[(size_t)s2*64 + lane];
    unsigned a3 = R[(size_t)s3*64 + lane];
    unsigned a4 = R[(size_t)s4*64 + lane];
    unsigned a5 = R[(size_t)s5*64 + lane];
    unsigned a6 = R[(size_t)s6*64 + lane];
    unsigned a7 = R[(size_t)s7*64 + lane];
    ax += bf_lo(a0); ay += bf_hi(a0);
    ax += bf_lo(a1); ay += bf_hi(a1);
    ax += bf_lo(a2); ay += bf_hi(a2);
    ax += bf_lo(a3); ay += bf_hi(a3);
    ax += bf_lo(a4); ay += bf_hi(a4);
    ax += bf_lo(a5); ay += bf_hi(a5);
    ax += bf_lo(a6); ay += bf_hi(a6);
    ax += bf_lo(a7); ay += bf_hi(a7);
  }
  for (; e < end; ++e){
    unsigned a0 = R[(size_t)col[e]*64 + lane];
    ax += bf_lo(a0); ay += bf_hi(a0);
  }
  float di = dinv[node];
  float2 bb = ((const float2*)bc)[lane];
  unsigned* H = (unsigned*)h;
  unsigned iu = H[(size_t)node*64 + lane];
  float vx = fmaf(ax, di, bb.x) + bf_lo(iu);
  float vy = fmaf(ay, di, bb.y) + bf_hi(iu);
  float s1 = vx + vy;
#pragma unroll
  for (int off=32; off; off>>=1) s1 += __shfl_xor(s1, off, 64);
  float mu = s1 * (1.0f/128.0f);
  float dx = vx - mu, dy = vy - mu;
  float q = dx*dx + dy*dy;
#pragma unroll
  for (int off=32; off; off>>=1) q += __shfl_xor(q, off, 64);
  float rstd = rsqrtf(q * (1.0f/128.0f) + 1e-5f);
  float2 gg = ((const float2*)g)[lane];
  float2 eb = ((const float2*)be)[lane];
  float ox = fmaxf(fmaf(dx*rstd, gg.x, eb.x), 0.f);
  float oy = fmaxf(fmaf(dy*rstd, gg.y, eb.y), 0.f);
  H[(size_t)node*64 + lane] = (unsigned)f2bf_rne(ox) | ((unsigned)f2bf_rne(oy) << 16);
}

// ---------------- output GEMM: [n,128]@[128,2] + bias ----------------
__global__ __launch_bounds__(256) void k_gemm_out(const unsigned short* __restrict__ h,
    const float* __restrict__ Wo, const float* __restrict__ bo,
    float* __restrict__ out, int n){
  int node = blockIdx.x*4 + (threadIdx.x >> 6);
  int lane = threadIdx.x & 63;
  if (node >= n) return;
  unsigned u = ((const unsigned*)h)[(size_t)node*64 + lane];
  float x = bf_lo(u), y = bf_hi(u);
  float4 w = ((const float4*)Wo)[lane];
  float p0 = x*w.x + y*w.z;
  float p1 = x*w.y + y*w.w;
#pragma unroll
  for (int off=32; off; off>>=1){
    p0 += __shfl_xor(p0, off, 64);
    p1 += __shfl_xor(p1, off, 64);
  }
  if (lane == 0){
    out[node*2+0] = p0 + bo[0];
    out[node*2+1] = p1 + bo[1];
  }
}

// =====================================================================
extern "C" void kernel_launch(void* const* d_in, const int* in_sizes, int n_in,
                              void* d_out, int out_size, void* d_ws, size_t ws_size,
                              hipStream_t stream){
  const float* x      = (const float*)d_in[0];
  const int*   ei     = (const int*)d_in[1];
  const float* W_in   = (const float*)d_in[2];
  const float* b_in   = (const float*)d_in[3];
  const float* W_out  = (const float*)d_in[4];
  const float* b_out  = (const float*)d_in[5];
  const float* Wc[3] = {(const float*)d_in[6],  (const float*)d_in[10], (const float*)d_in[14]};
  const float* bc[3] = {(const float*)d_in[7],  (const float*)d_in[11], (const float*)d_in[15]};
  const float* g[3]  = {(const float*)d_in[8],  (const float*)d_in[12], (const float*)d_in[16]};
  const float* be[3] = {(const float*)d_in[9],  (const float*)d_in[13], (const float*)d_in[17]};
  const int n = in_sizes[0] / 64;
  const int E = in_sizes[1] / 2;
  const int NB  = (n + 511) >> BSH;          // buckets of 512 nodes
  const int NCH = (E + CHUNK - 1) / CHUNK;   // edge chunks

  char* ws = (char*)d_ws;
  size_t off = 0;
  auto alloc = [&](size_t bytes)->char*{
    char* p = ws + off;
    off += (bytes + 511) & ~size_t(511);
    return p;
  };
  float* dinv   = (float*)alloc((size_t)n*4);
  int*   rp     = (int*)  alloc((size_t)(n+1)*4);
  int*   col    = (int*)  alloc((size_t)E*4);
  uint2* pairs  = (uint2*)alloc((size_t)E*8);
  int*   bh     = (int*)  alloc((size_t)NB*NCH*4);
  int*   btot   = (int*)  alloc((size_t)NB*4);
  int*   bstart = (int*)  alloc((size_t)(NB+1)*4);
  unsigned short* hB  = (unsigned short*)alloc((size_t)n*128*2);
  unsigned short* rows= (unsigned short*)alloc((size_t)n*128*2);
  unsigned short* Wt[3];
  for (int l = 0; l < 3; ++l) Wt[l] = (unsigned short*)alloc(128*128*2);
  (void)ws_size; (void)n_in; (void)out_size;

  // CSR build (no global atomics)
  k_bhist   <<<NCH, 256, 0, stream>>>(ei, E, n, NB, NCH, bh);
  k_scanB1  <<<NB, 256, 0, stream>>>(bh, btot, NCH);
  k_scanB2  <<<1, 512, 0, stream>>>(btot, bstart, NB, E, rp, n);
  k_bscatter<<<NCH, 256, 0, stream>>>(ei, E, n, NB, NCH, bh, bstart, pairs);
  k_brp     <<<NB, 256, 0, stream>>>(pairs, bstart, rp, dinv, n, NB);
  k_bfill   <<<NB, 256, 0, stream>>>(pairs, bstart, rp, col, n, NB);
  for (int l = 0; l < 3; ++l)
    k_prepW<<<64, 256, 0, stream>>>(Wc[l], Wt[l]);

  k_gemm_in<<<(n+63)/64, 256, 0, stream>>>(x, W_in, b_in, hB, n);
  for (int l = 0; l < 3; ++l){
    k_gemm_h_mfma<<<(n+63)/64, 256, 0, stream>>>(hB, Wt[l], dinv, rows, n);
    k_agg_ln <<<(n+3)/4, 256, 0, stream>>>(rows, hB, dinv, rp, col, bc[l], g[l], be[l], n);
  }
  k_gemm_out<<<(n+3)/4, 256, 0, stream>>>(hB, W_out, b_out, (float*)d_out, n);
}